// Round 20
// baseline (8051.686 us; speedup 1.0000x reference)
//
#include <hip/hip_runtime.h>
#include <math.h>

#define Bn 4096
#define Tn 128
#define Fn 96
#define Sn 128
#define Hn 512

typedef __attribute__((ext_vector_type(8))) short bf16x8;
typedef __attribute__((ext_vector_type(4))) float f32x4;

#define GC(p) ((const __attribute__((address_space(1))) void*)(p))
#define LC(p) ((__attribute__((address_space(3))) void*)(p))

__device__ __forceinline__ short tobf(float f){
  unsigned u = __float_as_uint(f);
  unsigned r = (u + 0x7fffu + ((u>>16)&1u)) >> 16;
  return (short)r;
}
__device__ __forceinline__ float bf2f(short s){
  return __uint_as_float(((unsigned)(unsigned short)s)<<16);
}
__device__ __forceinline__ float sigmf_(float x){ return 1.0f/(1.0f+expf(-x)); }

// swizzled offset for (row, c) within one [rows][64] bf16 chunk
__device__ __forceinline__ int sw64(int row, int c){
  return (row<<6) + ((((c>>3) ^ (row&7)))<<3) + (c&7);
}
// (row,k) in [nchunk][16][64] tile (16-row chunks) -- used by k_dec0
__device__ __forceinline__ int haddr(int row, int k){
  int c = k & 63;
  return ((k>>6)<<10) + (row<<6) + ((((c>>3) ^ (row&7)))<<3) + (c&7);
}

// stage `rows` rows (64 bf16 = 128B each) from gsrc into LDS tile, chunk-XOR swizzle.
__device__ __forceinline__ void stage_tile(const short* gsrc, size_t sstride, int k0,
                                           short* lt, int rows, int wid, int lane, int nw){
  int calls = rows >> 3;
  for (int c = wid; c < calls; c += nw){
    int r = (c<<3) + (lane>>3);
    int ch = (lane&7) ^ (r&7);
    const short* gp = gsrc + (size_t)r*sstride + k0 + (ch<<3);
    __builtin_amdgcn_global_load_lds(GC(gp), LC(lt + (c<<9)), 16, 0, 0);
  }
}
__device__ __forceinline__ bf16x8 frag(const short* lt, int row, int ch){
  return *(const bf16x8*)(lt + (row<<6) + ((ch ^ (row&7))<<3));
}

// ---------- prepacks ----------

__global__ void k_pack_td(const float* __restrict__ tdW, short* __restrict__ tdWp){
  int i = blockIdx.x*256 + threadIdx.x;            // 512*128
  if (i >= 512*128) return;
  int n = i>>7, k = i&127;
  tdWp[i] = (k < Fn) ? tobf(tdW[n*Fn + k]) : (short)0;
}
// Wxp K-order: [histW 512][realW 96][pad 32]  (matches xc A = [hdec|x])
__global__ void k_pack_x(const float* __restrict__ realW, const float* __restrict__ histW,
                         const float* __restrict__ realb, const float* __restrict__ histb,
                         short* __restrict__ Wxp, float* __restrict__ bxp){
  int i = blockIdx.x*256 + threadIdx.x;            // 96*640
  if (i < Fn) bxp[i] = realb[i] + histb[i];
  if (i >= Fn*640) return;
  int f = i/640, k = i - f*640;
  float v = 0.f;
  if (k < 512) v = histW[f*Hn + k];
  else if (k < 608) v = realW[f*Fn + (k-512)];
  Wxp[i] = tobf(v);
}
// Wgp: 8 panels x 256 ncols x 704 K; ncol = jj_local*4 + gate, jj = pb*64 + jj_local
__global__ void k_pack_g(const float* __restrict__ Wih, const float* __restrict__ Whh,
                         const float* __restrict__ bih, const float* __restrict__ bhh,
                         short* __restrict__ Wgp, float* __restrict__ bgp){
  int i = blockIdx.x*256 + threadIdx.x;            // 2048*704
  if (i >= 2048*704) return;
  int k = i % 704; int nc = i / 704;
  int pb = nc >> 8, ncol = nc & 255;
  int jj = pb*64 + (ncol >> 2), g = ncol & 3;
  int n = g*Hn + jj;
  float v;
  if (k < 512) v = Whh[(size_t)n*Hn + k];
  else if (k < 608) v = Wih[(size_t)n*192 + (k-512)];
  else v = Wih[(size_t)n*192 + 96 + (k-608)];
  Wgp[i] = tobf(v);
  if (k == 0) bgp[nc] = bih[n] + bhh[n];
}
__global__ void k_cvt(const float* __restrict__ src, short* __restrict__ dst, int n){
  int i = blockIdx.x*256 + threadIdx.x;
  if (i < n) dst[i] = tobf(src[i]);
}

// ---------- prologue math ----------

__global__ void k_static(const float* __restrict__ statics, const float* __restrict__ smask,
                         const float* __restrict__ frW, const float* __restrict__ frb,
                         float* __restrict__ s_c){
  __shared__ float row[Sn];
  int b = blockIdx.x, j = threadIdx.x;
  row[j] = statics[b*Sn + j];
  __syncthreads();
  float acc = frb[j];
  #pragma unroll 4
  for (int k = 0; k < Sn; k++) acc += row[k] * frW[j*Sn + k];
  float m = smask[b*Sn + j];
  s_c[b*Sn + j] = m * row[j] + (1.0f - m) * acc;
}

template<int K, bool RELU, bool WF32>
__global__ __launch_bounds__(512) void k_gemm(const short* __restrict__ A,
    const short* __restrict__ B, const float* __restrict__ bias,
    short* __restrict__ outb, float* __restrict__ outf){
  __shared__ __align__(16) short stA[2][8192], stB[2][8192];
  const int tid = threadIdx.x, lane = tid&63, wid = tid>>6;
  const int mb = blockIdx.x >> 2, nb = blockIdx.x & 3;
  const int r0 = mb*128, c0 = nb*128;
  const int wM = wid>>1, wN = wid&1, lr = lane&15, lq = lane>>4;
  f32x4 acc[2][4];
  #pragma unroll
  for (int m=0;m<2;m++)
    #pragma unroll
    for (int n=0;n<4;n++) acc[m][n] = (f32x4){0,0,0,0};
  constexpr int NS = K/64;
  stage_tile(A + (size_t)r0*K, K, 0, stA[0], 128, wid, lane, 8);
  stage_tile(B + (size_t)c0*K, K, 0, stB[0], 128, wid, lane, 8);
  __syncthreads();
  for (int kc=0; kc<NS; kc++){
    if (kc < NS-1){
      stage_tile(A + (size_t)r0*K, K, (kc+1)*64, stA[(kc+1)&1], 128, wid, lane, 8);
      stage_tile(B + (size_t)c0*K, K, (kc+1)*64, stB[(kc+1)&1], 128, wid, lane, 8);
    }
    #pragma unroll
    for (int kk=0;kk<2;kk++){
      int ch = (kk<<2) + lq;
      bf16x8 af[2];
      #pragma unroll
      for (int m=0;m<2;m++) af[m] = frag(stA[kc&1], wM*32 + m*16 + lr, ch);
      #pragma unroll
      for (int n=0;n<4;n++){
        bf16x8 bf = frag(stB[kc&1], wN*64 + n*16 + lr, ch);
        #pragma unroll
        for (int m=0;m<2;m++)
          acc[m][n] = __builtin_amdgcn_mfma_f32_16x16x32_bf16(af[m], bf, acc[m][n],0,0,0);
      }
    }
    __syncthreads();
  }
  #pragma unroll
  for (int m=0;m<2;m++)
    #pragma unroll
    for (int n=0;n<4;n++){
      int col = c0 + wN*64 + n*16 + lr;
      float bv = bias[col];
      #pragma unroll
      for (int reg=0;reg<4;reg++){
        int row = r0 + wM*32 + m*16 + (lq<<2) + reg;
        float v = acc[m][n][reg] + bv;
        if (RELU) v = fmaxf(v, 0.f);
        outb[(size_t)row*512 + col] = tobf(v);
        if (WF32) outf[(size_t)row*512 + col] = v;
      }
    }
}

template<int K, int N, bool RELU>
__global__ void k_mlp(const float* __restrict__ in, const float* __restrict__ W,
                      const float* __restrict__ bias, float* __restrict__ out){
  __shared__ float row[K];
  int b = blockIdx.x;
  for (int i = threadIdx.x; i < K; i += blockDim.x) row[i] = in[b*K + i];
  __syncthreads();
  for (int n = threadIdx.x; n < N; n += blockDim.x){
    float acc = bias[n];
    #pragma unroll 4
    for (int k = 0; k < K; k++) acc += row[k] * W[n*K + k];
    if (RELU) acc = fmaxf(acc, 0.0f);
    out[b*N + n] = acc;
  }
}

// ---------- bootstrap: hdec(0) = h0 * gamma(0) -> inp0 (stride 512) ----------
__global__ __launch_bounds__(512) void k_dec0(
    const float* __restrict__ deltas, const short* __restrict__ tdWp,
    const float* __restrict__ tdb, const float* __restrict__ h_g,
    short* __restrict__ inp){
  __shared__ __align__(16) short Adel[2*1024];
  __shared__ __align__(16) short Bbig[65536];
  const int tid = threadIdx.x, lane = tid&63, wid = tid>>6;
  const int r0 = blockIdx.x*16;
  const int lr = lane&15, lq = lane>>4;

  float4 dv4;
  const bool act = tid < 384;
  int ar=0, af0=0;
  if (act){
    ar = tid/24; af0 = (tid - ar*24)*4;
    dv4 = *(const float4*)(deltas + (size_t)(r0+ar)*Tn*Fn + af0);   // t=0
  }
  float hreg[16];
  #pragma unroll
  for (int nq=0;nq<4;nq++){
    int col = nq*128 + wid*16 + lr;
    #pragma unroll
    for (int reg=0;reg<4;reg++)
      hreg[nq*4+reg] = h_g[(size_t)(r0 + (lq<<2) + reg)*Hn + col];
  }
  #pragma unroll
  for (int s=0; s<8; s++)
    stage_tile(tdWp + (size_t)((s>>1)*128)*128, 128, (s&1)*64, Bbig + s*8192, 128, wid, lane, 8);
  if (act){
    #pragma unroll
    for (int j=0;j<4;j++)
      Adel[haddr(ar, af0+j)] = tobf(((const float*)&dv4)[j]);
  }
  { int r = tid>>5, cz = tid&31; Adel[haddr(r, 96+cz)] = 0; }
  __syncthreads();

  f32x4 accd[4];
  #pragma unroll
  for (int q=0;q<4;q++) accd[q] = (f32x4){0,0,0,0};
  #pragma unroll
  for (int s=0; s<8; s++){
    int nq = s>>1, kc = s&1;
    #pragma unroll
    for (int kk=0;kk<2;kk++){
      int ch = (kk<<2) + lq;
      bf16x8 afr = frag(Adel + kc*1024, lr, ch);
      bf16x8 bfr = frag(Bbig + s*8192, wid*16 + lr, ch);
      accd[nq] = __builtin_amdgcn_mfma_f32_16x16x32_bf16(afr, bfr, accd[nq], 0,0,0);
    }
  }
  #pragma unroll
  for (int nq=0;nq<4;nq++){
    int col = nq*128 + wid*16 + lr;
    float tb = tdb[col];
    #pragma unroll
    for (int reg=0;reg<4;reg++){
      int row = (lq<<2) + reg;
      float v = accd[nq][reg] + tb;
      inp[(size_t)(r0+row)*512 + col] = tobf(hreg[nq*4+reg] * __expf(-fmaxf(v,0.f)));
    }
  }
}

// ---------- THE per-step kernel: xc (redundant per panel) + gates + LSTM + gamma tail ----------
// grid 256 = 32 row-slabs (mb) x 8 gate-panels (pb); 512 threads; 1 blk/CU.
// LDS POOL (shorts): ccm 3x8192 @0 (K 512..703: cc|m), xA 2x8192 @24576
// (phase1: x chunks; phase2: hdec A-dbuf; tail: dA), region2 @40960:
// phase1 A-dbuf 2x8192 + Wxp dbuf 2x6144; phase2 B-dbuf 2x16384; tail tdW+vlds.
__global__ __launch_bounds__(512) void k_sg(int t,
    const float* __restrict__ values, const float* __restrict__ masks,
    const float* __restrict__ deltas,
    const short* __restrict__ Wxp,  const float* __restrict__ bxp,
    const float* __restrict__ st,   const short* __restrict__ Wgp,
    const float* __restrict__ bgp,  const short* __restrict__ tdWp,
    const float* __restrict__ tdb,
    const short* __restrict__ inpR, short* __restrict__ inpW,
    float* __restrict__ h_g, float* __restrict__ c_g,
    float* __restrict__ out_imp, float* __restrict__ num, float* __restrict__ den){
  __shared__ __align__(16) short P[73728];   // 144 KB
  __shared__ float wred[8], wred2[8];
  short* ccm  = P;           // chunks 0,1,2 -> K 512..575, 576..639, 640..703
  short* xA   = P + 24576;   // 2 chunks
  short* aD   = P + 40960;   // phase1 A-dbuf (2 x 8192)
  short* bD   = P + 57344;   // phase1 Wxp dbuf (2 x 6144)
  short* gB   = P + 40960;   // phase2 B-dbuf (2 x 16384)
  short* tdS  = P + 40960;   // tail tdW slice (2 x 4096)
  float* vlds = (float*)(P + 49152);  // tail gamma [128][65] f32
  const int tid = threadIdx.x, lane = tid&63, w = tid>>6;
  const int pb = blockIdx.x & 7, mb = blockIdx.x >> 3;
  const int r0 = mb*128;
  const int lr = lane&15, lq = lane>>4;
  const bool hg = (t+1 < Tn);

  // ---- entry: load x/m (24 cols per thread), issue phase1 stage 0 ----
  const int ir = tid>>2, ic0 = (tid&3)*24;
  float xr[24], mr[24];
  {
    size_t gb2 = ((size_t)(r0+ir)*Tn + t)*Fn + ic0;
    #pragma unroll
    for (int q=0;q<6;q++){
      float4 xv = *(const float4*)(values + gb2 + q*4);
      float4 mv = *(const float4*)(masks  + gb2 + q*4);
      xr[q*4+0]=xv.x; xr[q*4+1]=xv.y; xr[q*4+2]=xv.z; xr[q*4+3]=xv.w;
      mr[q*4+0]=mv.x; mr[q*4+1]=mv.y; mr[q*4+2]=mv.z; mr[q*4+3]=mv.w;
    }
  }
  stage_tile(inpR + (size_t)r0*512, 512, 0, aD, 128, w, lane, 8);
  stage_tile(Wxp, 640, 0, bD, 96, w, lane, 8);

  // build xA (x at local K 0..95 of [x|pad]) and ccm m-region (K 608..703)
  #pragma unroll
  for (int j=0;j<24;j++){
    int f = ic0 + j;
    xA[((f>>6)<<13) + sw64(ir, f&63)] = tobf(xr[j]);
    int km = 608 + f;               // chunk (km>>6)-8 = 1 or 2
    ccm[(((km>>6)-8)<<13) + sw64(ir, km&63)] = tobf(mr[j]);
  }
  #pragma unroll
  for (int j=0;j<8;j++){            // x pad cols 96..127 -> xA chunk1 cols 32..63
    int cz = 32 + (tid&3)*8 + j;
    xA[8192 + sw64(ir, cz)] = 0;
  }
  __syncthreads();   // bar1

  // ---- phase 1: xc GEMM M=128, N=96 (waves 0..5), K=640 ----
  f32x4 accx[8];
  #pragma unroll
  for (int m=0;m<8;m++) accx[m] = (f32x4){0,0,0,0};
  for (int kx=0; kx<10; kx++){
    if (kx < 9){
      if (kx+1 < 8)
        stage_tile(inpR + (size_t)r0*512, 512, (kx+1)*64, aD + ((kx+1)&1)*8192, 128, w, lane, 8);
      stage_tile(Wxp, 640, (kx+1)*64, bD + ((kx+1)&1)*6144, 96, w, lane, 8);
    }
    const short* Ac = (kx<8) ? (aD + (kx&1)*8192) : (xA + (kx-8)*8192);
    const short* Bc = bD + (kx&1)*6144;
    if (w < 6){
      #pragma unroll
      for (int kk=0;kk<2;kk++){
        int ch = (kk<<2) + lq;
        bf16x8 bfr = frag(Bc, w*16 + lr, ch);
        #pragma unroll
        for (int m=0;m<8;m++)
          accx[m] = __builtin_amdgcn_mfma_f32_16x16x32_bf16(frag(Ac, m*16+lr, ch), bfr, accx[m],0,0,0);
      }
    }
    __syncthreads();
  }
  // phase1 epilogue: cc -> ccm; pb==0 writes out_imp + loss sums
  float lsum = 0.f, msum = 0.f;
  if (w < 6){
    int f = w*16 + lr;
    float bx = bxp[f];
    #pragma unroll
    for (int m=0;m<8;m++)
      #pragma unroll
      for (int reg=0;reg<4;reg++){
        int row = m*16 + (lq<<2) + reg;
        float xcv = accx[m][reg] + bx + st[(size_t)(r0+row)*Fn + f];
        float xv = bf2f(xA[((f>>6)<<13) + sw64(row, f&63)]);
        int km = 608 + f;
        float mv = bf2f(ccm[(((km>>6)-8)<<13) + sw64(row, km&63)]);
        lsum += fabsf(xv - xcv)*mv;
        msum += mv;
        float cc = mv*xv + (1.f-mv)*xcv;
        ccm[((f>>6)<<13) + sw64(row, f&63)] = tobf(cc);
        if (pb == 0) out_imp[((size_t)(r0+row)*Tn + t)*Fn + f] = cc;
      }
  }
  #pragma unroll
  for (int o=32;o>0;o>>=1){ lsum += __shfl_down(lsum, o); msum += __shfl_down(msum, o); }
  if (lane==0){ wred[w] = lsum; wred2[w] = msum; }
  __syncthreads();   // bar2: cc visible, xA free
  if (tid==0 && pb==0){
    float s2 = 0.f, s3 = 0.f;
    #pragma unroll
    for (int w2=0;w2<8;w2++){ s2 += wred[w2]; s3 += wred2[w2]; }
    atomicAdd(&num[t], s2);
    atomicAdd(&den[t], s3);
  }

  // ---- phase 2: gates GEMM M=128, N=256 (panel pb), K=704 ----
  const short* WgB = Wgp + (size_t)pb*256*704;
  stage_tile(inpR + (size_t)r0*512, 512, 0, xA, 128, w, lane, 8);   // A0 (hdec c0)
  stage_tile(WgB, 704, 0, gB, 256, w, lane, 8);                     // B0
  __syncthreads();   // bar3

  const int wM = w>>2, wN = w&3;   // 2M x 4N; wave owns 64 rows x 64 ncols
  f32x4 acc[4][4];
  #pragma unroll
  for (int m=0;m<4;m++)
    #pragma unroll
    for (int n=0;n<4;n++) acc[m][n] = (f32x4){0,0,0,0};

  for (int kc=0; kc<11; kc++){
    if (kc < 10){
      if (kc+1 < 8)
        stage_tile(inpR + (size_t)r0*512, 512, (kc+1)*64, xA + ((kc+1)&1)*8192, 128, w, lane, 8);
      stage_tile(WgB, 704, (kc+1)*64, gB + ((kc+1)&1)*16384, 256, w, lane, 8);
    }
    const short* Ac = (kc<8) ? (xA + (kc&1)*8192) : (ccm + (kc-8)*8192);
    const short* Bc = gB + (kc&1)*16384;
    #pragma unroll
    for (int kk=0;kk<2;kk++){
      int ch = (kk<<2) + lq;
      bf16x8 af[4];
      #pragma unroll
      for (int m=0;m<4;m++) af[m] = frag(Ac, wM*64 + m*16 + lr, ch);
      #pragma unroll
      for (int n=0;n<4;n++){
        bf16x8 bf = frag(Bc, wN*64 + n*16 + lr, ch);
        #pragma unroll
        for (int m=0;m<4;m++)
          acc[m][n] = __builtin_amdgcn_mfma_f32_16x16x32_bf16(af[m], bf, acc[m][n],0,0,0);
      }
    }
    __syncthreads();
  }

  // tail staging issued early: deltas(t+1) -> regs; tdW slice -> tdS
  float dreg[24];
  if (hg){
    size_t gb2 = ((size_t)(r0+ir)*Tn + (t+1))*Fn + ic0;
    #pragma unroll
    for (int q=0;q<6;q++){
      float4 v4 = *(const float4*)(deltas + gb2 + q*4);
      dreg[q*4+0]=v4.x; dreg[q*4+1]=v4.y; dreg[q*4+2]=v4.z; dreg[q*4+3]=v4.w;
    }
    stage_tile(tdWp + (size_t)(pb*64)*128, 128, 0,  tdS,        64, w, lane, 8);
    stage_tile(tdWp + (size_t)(pb*64)*128, 128, 64, tdS + 4096, 64, w, lane, 8);
  }

  // LSTM epilogue (ncol = jj_local*4 + g; 4-lane shfl transpose)
  const int g = lane&3;
  const float s_  = (g==2) ? 2.0f : -1.0f;
  const float ca_ = (g==2) ? -2.0f : 1.0f;
  const float cb_ = (g==2) ? 1.0f : 0.0f;
  float hnew[4][4];
  #pragma unroll
  for (int m=0;m<4;m++){
    int row = r0 + wM*64 + m*16 + (lq<<2) + g;
    #pragma unroll
    for (int n=0;n<4;n++){
      int colbase = wN*64 + n*16 + lr;
      float b = bgp[pb*256 + colbase];
      float q0 = 1.f/(1.f+__expf(s_*(acc[m][n][0]+b))); float a0 = q0*ca_+cb_;
      float q1 = 1.f/(1.f+__expf(s_*(acc[m][n][1]+b))); float a1 = q1*ca_+cb_;
      float q2 = 1.f/(1.f+__expf(s_*(acc[m][n][2]+b))); float a2 = q2*ca_+cb_;
      float q3 = 1.f/(1.f+__expf(s_*(acc[m][n][3]+b))); float a3 = q3*ca_+cb_;
      int i1=g^1, i2=g^2, i3=g^3;
      float p1 = (i1==0)?a0:(i1==1)?a1:(i1==2)?a2:a3;
      float p2 = (i2==0)?a0:(i2==1)?a1:(i2==2)?a2:a3;
      float p3 = (i3==0)?a0:(i3==1)?a1:(i3==2)?a2:a3;
      float ow = (g==0)?a0:(g==1)?a1:(g==2)?a2:a3;
      float t1 = __shfl_xor(p1, 1, 64);
      float t2 = __shfl_xor(p2, 2, 64);
      float t3 = __shfl_xor(p3, 3, 64);
      float si = (g==0)?ow:(g==1)?t1:(g==2)?t2:t3;
      float sf = (g==1)?ow:(g==0)?t1:(g==3)?t2:t3;
      float tg = (g==2)?ow:(g==3)?t1:(g==0)?t2:t3;
      float so = (g==3)?ow:(g==2)?t1:(g==1)?t2:t3;
      int jh = pb*64 + (colbase>>2);
      size_t idx = (size_t)row*Hn + jh;
      float co = c_g[idx];
      float cn = sf*co + si*tg;
      float targ = fminf(fmaxf(2.0f*cn,-60.f),60.f);
      float e = __expf(targ); float th = (e-1.f)/(e+1.f);
      c_g[idx] = cn;
      float hv = so*th;
      h_g[idx] = hv;
      hnew[m][n] = hv;
    }
  }

  if (hg){
    // dA build in xA region (free after kc=7) + zero pad 96..127
    #pragma unroll
    for (int j=0;j<24;j++){
      int cdx = ic0 + j;
      xA[((cdx>>6)<<13) + sw64(ir, cdx&63)] = tobf(dreg[j]);
    }
    #pragma unroll
    for (int j=0;j<8;j++){
      int cz = 32 + (tid&3)*8 + j;
      xA[8192 + sw64(ir, cz)] = 0;
    }
    __syncthreads();   // bar4: dA + tdS ready

    // gamma MFMA: M=128 (wave w: rows w*16..+15), N=64, K=128
    f32x4 gv[4];
    #pragma unroll
    for (int n=0;n<4;n++) gv[n] = (f32x4){0,0,0,0};
    #pragma unroll
    for (int kc=0;kc<2;kc++)
      #pragma unroll
      for (int kk=0;kk<2;kk++){
        int ch = (kk<<2) + lq;
        bf16x8 afr = frag(xA + kc*8192, w*16 + lr, ch);
        #pragma unroll
        for (int n=0;n<4;n++)
          gv[n] = __builtin_amdgcn_mfma_f32_16x16x32_bf16(afr,
                    frag(tdS + kc*4096, n*16 + lr, ch), gv[n], 0,0,0);
      }
    #pragma unroll
    for (int n=0;n<4;n++)
      #pragma unroll
      for (int reg=0;reg<4;reg++)
        vlds[(w*16 + (lq<<2) + reg)*65 + n*16 + lr] = gv[n][reg];
    __syncthreads();   // bar5

    // hdec(t+1) = hnew * gamma -> inpW
    #pragma unroll
    for (int m=0;m<4;m++){
      int rowl = wM*64 + m*16 + (lq<<2) + g;
      #pragma unroll
      for (int n=0;n<4;n++){
        int jl = (wN*64 + n*16 + lr)>>2;
        float v = vlds[rowl*65 + jl] + tdb[pb*64 + jl];
        float gam = __expf(-fmaxf(v, 0.f));
        inpW[(size_t)(r0+rowl)*512 + pb*64 + jl] = tobf(hnew[m][n] * gam);
      }
    }
  }
}

// ---------- epilogue ----------

__global__ void k_out(const float* __restrict__ h_g, const float* __restrict__ outW,
                      const float* __restrict__ outb, const float* __restrict__ labels,
                      float* __restrict__ out_sig, float* __restrict__ yacc){
  int b = blockIdx.x, lane = threadIdx.x;
  float s = 0.f;
  for (int k = lane; k < Hn; k += 64) s += h_g[(size_t)b*Hn + k] * outW[k];
  #pragma unroll
  for (int o = 32; o > 0; o >>= 1) s += __shfl_down(s, o);
  if (lane == 0){
    float z = s + outb[0];
    out_sig[b] = sigmf_(z);
    float yl = fmaxf(z, 0.f) - z*labels[b] + log1pf(expf(-fabsf(z)));
    atomicAdd(yacc, yl);
  }
}

__global__ void k_loss(const float* __restrict__ realW, const float* __restrict__ histW,
                       const float* __restrict__ stW,   const float* __restrict__ frW,
                       const float* __restrict__ num,   const float* __restrict__ den,
                       const float* __restrict__ yacc,  float* __restrict__ out0){
  int tid = threadIdx.x;
  float r1 = 0.f;
  for (int i = tid; i < Fn*Fn; i += 256) r1 += fabsf(realW[i]);
  for (int i = tid; i < Fn*Hn; i += 256) r1 += fabsf(histW[i]);
  for (int i = tid; i < Fn*Sn; i += 256) r1 += fabsf(stW[i]);
  float rd = 0.f;
  for (int i = tid; i < Fn; i += 256) rd += fabsf(realW[i*Fn + i]);
  float fd = 0.f;
  for (int i = tid; i < Sn; i += 256) fd += fabsf(frW[i*Sn + i]);
  float xl = 0.f;
  for (int t = tid; t < Tn; t += 256) xl += num[t] / (den[t] + 1e-5f);
  float v = 0.01f*r1 + 0.1f*rd + 0.3f*xl + 0.03f*fd;
  __shared__ float red[256];
  red[tid] = v; __syncthreads();
  for (int o = 128; o > 0; o >>= 1){ if (tid < o) red[tid] += red[tid + o]; __syncthreads(); }
  if (tid == 0) out0[0] = red[0] + yacc[0] / (float)Bn;
}

// ---------- launch ----------

extern "C" void kernel_launch(void* const* d_in, const int* in_sizes, int n_in,
                              void* d_out, int out_size, void* d_ws, size_t ws_size,
                              hipStream_t stream){
  const float* values = (const float*)d_in[0];
  const float* masks  = (const float*)d_in[1];
  const float* deltas = (const float*)d_in[2];
  const float* statics= (const float*)d_in[3];
  const float* smask  = (const float*)d_in[4];
  const float* labels = (const float*)d_in[5];
  const float* frW = (const float*)d_in[6];
  const float* frb = (const float*)d_in[7];
  const float* d1W = (const float*)d_in[8];
  const float* d1b = (const float*)d_in[9];
  const float* d2W = (const float*)d_in[10];
  const float* d2b = (const float*)d_in[11];
  const float* d3W = (const float*)d_in[12];
  const float* d3b = (const float*)d_in[13];
  const float* tdW = (const float*)d_in[14];
  const float* tdb = (const float*)d_in[15];
  const float* histW = (const float*)d_in[16];
  const float* histb = (const float*)d_in[17];
  const float* stW = (const float*)d_in[18];
  const float* stb = (const float*)d_in[19];
  const float* realW = (const float*)d_in[20];
  const float* realb = (const float*)d_in[21];
  const float* Wih = (const float*)d_in[22];
  const float* Whh = (const float*)d_in[23];
  const float* bih = (const float*)d_in[24];
  const float* bhh = (const float*)d_in[25];
  const float* outW = (const float*)d_in[26];
  const float* outb = (const float*)d_in[27];

  float* out0    = (float*)d_out;
  float* out_sig = out0 + 1;
  float* out_imp = out0 + 1 + Bn;

  float* wsf  = (float*)d_ws;
  float* s_c  = wsf;  wsf += Bn*Sn;
  float* h    = wsf;  wsf += (size_t)Bn*Hn;
  float* c    = wsf;  wsf += (size_t)Bn*Hn;
  float* st   = wsf;  wsf += Bn*Fn;
  float* den  = wsf;  wsf += Tn;
  float* num  = wsf;  wsf += Tn;
  float* yacc = num + Tn;           // den/num/yacc contiguous, zeroed together
  wsf += 1;
  float* bxp  = wsf;  wsf += 128;
  float* bgp  = wsf;  wsf += 2048;
  size_t off = ((size_t)(wsf - (float*)d_ws) + 3u) & ~(size_t)3u;
  short* wss  = (short*)((float*)d_ws + off);
  short* tdWp = wss;  wss += 512*128;
  short* Wxp  = wss;  wss += 96*640;
  short* Wgp  = wss;  wss += (size_t)2048*704;
  short* inp0 = wss;  wss += (size_t)Bn*512;
  short* inp1 = wss;  wss += (size_t)Bn*512;
  short* wd1  = wss;  wss += 512*128;
  short* wd2  = wss;  wss += 512*512;
  short* wd3  = wss;  wss += 512*512;
  short* act0 = wss;  wss += (size_t)Bn*128;
  short* actA = wss;  wss += (size_t)Bn*512;
  short* actB = wss;  wss += (size_t)Bn*512;

  hipMemsetAsync(c,   0, (size_t)Bn*Hn*sizeof(float), stream);
  hipMemsetAsync(den, 0, (2*Tn + 1)*sizeof(float), stream);

  // prepacks
  k_pack_td<<<(512*128+255)/256, 256, 0, stream>>>(tdW, tdWp);
  k_pack_x <<<(96*640+255)/256, 256, 0, stream>>>(realW, histW, realb, histb, Wxp, bxp);
  k_pack_g <<<(2048*704+255)/256, 256, 0, stream>>>(Wih, Whh, bih, bhh, Wgp, bgp);
  k_cvt<<<(512*128+255)/256, 256, 0, stream>>>(d1W, wd1, 512*128);
  k_cvt<<<(512*512+255)/256, 256, 0, stream>>>(d2W, wd2, 512*512);
  k_cvt<<<(512*512+255)/256, 256, 0, stream>>>(d3W, wd3, 512*512);

  // prologue math: static imputation + MFMA MLP chain
  k_static<<<Bn, Sn, 0, stream>>>(statics, smask, frW, frb, s_c);
  k_cvt<<<(Bn*Sn+255)/256, 256, 0, stream>>>(s_c, act0, Bn*Sn);
  k_gemm<128, true,  false><<<128, 512, 0, stream>>>(act0, wd1, d1b, actA, (float*)nullptr);
  k_gemm<512, true,  false><<<128, 512, 0, stream>>>(actA, wd2, d2b, actB, (float*)nullptr);
  k_gemm<512, true,  true ><<<128, 512, 0, stream>>>(actB, wd3, d3b, actA, h);
  k_mlp<Sn, Fn, false><<<Bn, 256, 0, stream>>>(s_c, stW, stb, st);

  // bootstrap hdec(0)
  k_dec0<<<Bn/16, 512, 0, stream>>>(deltas, tdWp, tdb, h, inp0);

  // scan: ONE dispatch per step; hdec double-buffered by parity
  for (int t = 0; t < Tn; t++){
    short* iR = (t & 1) ? inp1 : inp0;
    short* iW = (t & 1) ? inp0 : inp1;
    k_sg<<<256, 512, 0, stream>>>(t, values, masks, deltas, Wxp, bxp, st,
                                  Wgp, bgp, tdWp, tdb, iR, iW, h, c,
                                  out_imp, num, den);
  }

  k_out<<<Bn, 64, 0, stream>>>(h, outW, outb, labels, out_sig, yacc);
  k_loss<<<1, 256, 0, stream>>>(realW, histW, stW, frW, num, den, yacc, out0);
}

// Round 21
// 5293.828 us; speedup vs baseline: 1.5210x; 1.5210x over previous
//
#include <hip/hip_runtime.h>
#include <math.h>

#define Bn 4096
#define Tn 128
#define Fn 96
#define Sn 128
#define Hn 512

typedef __attribute__((ext_vector_type(8))) short bf16x8;
typedef __attribute__((ext_vector_type(4))) float f32x4;

#define GC(p) ((const __attribute__((address_space(1))) void*)(p))
#define LC(p) ((__attribute__((address_space(3))) void*)(p))

__device__ __forceinline__ short tobf(float f){
  unsigned u = __float_as_uint(f);
  unsigned r = (u + 0x7fffu + ((u>>16)&1u)) >> 16;
  return (short)r;
}
__device__ __forceinline__ float bf2f(short s){
  return __uint_as_float(((unsigned)(unsigned short)s)<<16);
}
__device__ __forceinline__ float sigmf_(float x){ return 1.0f/(1.0f+expf(-x)); }

// swizzled offset for (row, k) in [nchunk][16][64] LDS tile (16-row chunks)
__device__ __forceinline__ int haddr(int row, int k){
  int c = k & 63;
  return ((k>>6)<<10) + (row<<6) + ((((c>>3) ^ (row&7)))<<3) + (c&7);
}
// swizzled offset for (row, k) in [nchunk][128][64] LDS tile (128-row chunks)
__device__ __forceinline__ int haddr128(int row, int k){
  int c = k & 63;
  return ((k>>6)<<13) + (row<<6) + ((((c>>3) ^ (row&7)))<<3) + (c&7);
}

// stage `rows` rows (64 bf16 = 128B each) from gsrc into LDS tile, chunk-XOR swizzle.
__device__ __forceinline__ void stage_tile(const short* gsrc, size_t sstride, int k0,
                                           short* lt, int rows, int wid, int lane, int nw){
  int calls = rows >> 3;
  for (int c = wid; c < calls; c += nw){
    int r = (c<<3) + (lane>>3);
    int ch = (lane&7) ^ (r&7);
    const short* gp = gsrc + (size_t)r*sstride + k0 + (ch<<3);
    __builtin_amdgcn_global_load_lds(GC(gp), LC(lt + (c<<9)), 16, 0, 0);
  }
}
__device__ __forceinline__ bf16x8 frag(const short* lt, int row, int ch){
  return *(const bf16x8*)(lt + (row<<6) + ((ch ^ (row&7))<<3));
}

// ---------- prepacks ----------

__global__ void k_pack_td(const float* __restrict__ tdW, short* __restrict__ tdWp){
  int i = blockIdx.x*256 + threadIdx.x;            // 512*128
  if (i >= 512*128) return;
  int n = i>>7, k = i&127;
  tdWp[i] = (k < Fn) ? tobf(tdW[n*Fn + k]) : (short)0;
}
// Wxp K-order: [histW 512][realW 96][pad 32]  (matches A2 = [hdec|x])
__global__ void k_pack_x(const float* __restrict__ realW, const float* __restrict__ histW,
                         const float* __restrict__ realb, const float* __restrict__ histb,
                         short* __restrict__ Wxp, float* __restrict__ bxp){
  int i = blockIdx.x*256 + threadIdx.x;            // 96*640
  if (i < Fn) bxp[i] = realb[i] + histb[i];
  if (i >= Fn*640) return;
  int f = i/640, k = i - f*640;
  float v = 0.f;
  if (k < 512) v = histW[f*Hn + k];
  else if (k < 608) v = realW[f*Fn + (k-512)];
  Wxp[i] = tobf(v);
}
// Wgp: 16 panels x 128 ncols x 704 K; ncol = jj_local*4 + gate, jj = pb*32 + jj_local
__global__ void k_pack_g(const float* __restrict__ Wih, const float* __restrict__ Whh,
                         const float* __restrict__ bih, const float* __restrict__ bhh,
                         short* __restrict__ Wgp, float* __restrict__ bgp){
  int i = blockIdx.x*256 + threadIdx.x;            // 16*128*704
  if (i >= 16*128*704) return;
  int k = i % 704; int nc = i / 704;
  int pb = nc >> 7, ncol = nc & 127;
  int jj = pb*32 + (ncol >> 2), g = ncol & 3;
  int n = g*Hn + jj;
  float v;
  if (k < 512) v = Whh[(size_t)n*Hn + k];
  else if (k < 608) v = Wih[(size_t)n*192 + (k-512)];
  else v = Wih[(size_t)n*192 + 96 + (k-608)];
  Wgp[i] = tobf(v);
  if (k == 0) bgp[nc] = bih[n] + bhh[n];
}
// generic fp32 -> bf16 convert
__global__ void k_cvt(const float* __restrict__ src, short* __restrict__ dst, int n){
  int i = blockIdx.x*256 + threadIdx.x;
  if (i < n) dst[i] = tobf(src[i]);
}

// ---------- prologue math ----------

__global__ void k_static(const float* __restrict__ statics, const float* __restrict__ smask,
                         const float* __restrict__ frW, const float* __restrict__ frb,
                         float* __restrict__ s_c){
  __shared__ float row[Sn];
  int b = blockIdx.x, j = threadIdx.x;
  row[j] = statics[b*Sn + j];
  __syncthreads();
  float acc = frb[j];
  #pragma unroll 4
  for (int k = 0; k < Sn; k++) acc += row[k] * frW[j*Sn + k];
  float m = smask[b*Sn + j];
  s_c[b*Sn + j] = m * row[j] + (1.0f - m) * acc;
}

// bf16 MFMA GEMM: out[4096x512] = act(A[4096xK] @ B[512xK]^T + bias)
template<int K, bool RELU, bool WF32>
__global__ __launch_bounds__(512) void k_gemm(const short* __restrict__ A,
    const short* __restrict__ B, const float* __restrict__ bias,
    short* __restrict__ outb, float* __restrict__ outf){
  __shared__ __align__(16) short stA[2][8192], stB[2][8192];
  const int tid = threadIdx.x, lane = tid&63, wid = tid>>6;
  const int mb = blockIdx.x >> 2, nb = blockIdx.x & 3;
  const int r0 = mb*128, c0 = nb*128;
  const int wM = wid>>1, wN = wid&1, lr = lane&15, lq = lane>>4;
  f32x4 acc[2][4];
  #pragma unroll
  for (int m=0;m<2;m++)
    #pragma unroll
    for (int n=0;n<4;n++) acc[m][n] = (f32x4){0,0,0,0};
  constexpr int NS = K/64;
  stage_tile(A + (size_t)r0*K, K, 0, stA[0], 128, wid, lane, 8);
  stage_tile(B + (size_t)c0*K, K, 0, stB[0], 128, wid, lane, 8);
  __syncthreads();
  for (int kc=0; kc<NS; kc++){
    if (kc < NS-1){
      stage_tile(A + (size_t)r0*K, K, (kc+1)*64, stA[(kc+1)&1], 128, wid, lane, 8);
      stage_tile(B + (size_t)c0*K, K, (kc+1)*64, stB[(kc+1)&1], 128, wid, lane, 8);
    }
    #pragma unroll
    for (int kk=0;kk<2;kk++){
      int ch = (kk<<2) + lq;
      bf16x8 af[2];
      #pragma unroll
      for (int m=0;m<2;m++) af[m] = frag(stA[kc&1], wM*32 + m*16 + lr, ch);
      #pragma unroll
      for (int n=0;n<4;n++){
        bf16x8 bf = frag(stB[kc&1], wN*64 + n*16 + lr, ch);
        #pragma unroll
        for (int m=0;m<2;m++)
          acc[m][n] = __builtin_amdgcn_mfma_f32_16x16x32_bf16(af[m], bf, acc[m][n],0,0,0);
      }
    }
    __syncthreads();
  }
  #pragma unroll
  for (int m=0;m<2;m++)
    #pragma unroll
    for (int n=0;n<4;n++){
      int col = c0 + wN*64 + n*16 + lr;
      float bv = bias[col];
      #pragma unroll
      for (int reg=0;reg<4;reg++){
        int row = r0 + wM*32 + m*16 + (lq<<2) + reg;
        float v = acc[m][n][reg] + bv;
        if (RELU) v = fmaxf(v, 0.f);
        outb[(size_t)row*512 + col] = tobf(v);
        if (WF32) outf[(size_t)row*512 + col] = v;
      }
    }
}

template<int K, int N, bool RELU>
__global__ void k_mlp(const float* __restrict__ in, const float* __restrict__ W,
                      const float* __restrict__ bias, float* __restrict__ out){
  __shared__ float row[K];
  int b = blockIdx.x;
  for (int i = threadIdx.x; i < K; i += blockDim.x) row[i] = in[b*K + i];
  __syncthreads();
  for (int n = threadIdx.x; n < N; n += blockDim.x){
    float acc = bias[n];
    #pragma unroll 4
    for (int k = 0; k < K; k++) acc += row[k] * W[n*K + k];
    if (RELU) acc = fmaxf(acc, 0.0f);
    out[b*N + n] = acc;
  }
}

// ---------- bootstrap: hdec(0) = h0 * gamma(0) -> inp0 ----------
__global__ __launch_bounds__(512) void k_dec0(
    const float* __restrict__ deltas, const short* __restrict__ tdWp,
    const float* __restrict__ tdb, const float* __restrict__ h_g,
    short* __restrict__ inp){
  __shared__ __align__(16) short Adel[2*1024];
  __shared__ __align__(16) short Bbig[65536];
  const int tid = threadIdx.x, lane = tid&63, wid = tid>>6;
  const int r0 = blockIdx.x*16;
  const int lr = lane&15, lq = lane>>4;

  float4 dv4;
  const bool act = tid < 384;
  int ar=0, af0=0;
  if (act){
    ar = tid/24; af0 = (tid - ar*24)*4;
    dv4 = *(const float4*)(deltas + (size_t)(r0+ar)*Tn*Fn + af0);   // t=0
  }
  float hreg[16];
  #pragma unroll
  for (int nq=0;nq<4;nq++){
    int col = nq*128 + wid*16 + lr;
    #pragma unroll
    for (int reg=0;reg<4;reg++)
      hreg[nq*4+reg] = h_g[(size_t)(r0 + (lq<<2) + reg)*Hn + col];
  }
  #pragma unroll
  for (int s=0; s<8; s++)
    stage_tile(tdWp + (size_t)((s>>1)*128)*128, 128, (s&1)*64, Bbig + s*8192, 128, wid, lane, 8);
  if (act){
    #pragma unroll
    for (int j=0;j<4;j++)
      Adel[haddr(ar, af0+j)] = tobf(((const float*)&dv4)[j]);
  }
  { int r = tid>>5, cz = tid&31; Adel[haddr(r, 96+cz)] = 0; }
  __syncthreads();

  f32x4 accd[4];
  #pragma unroll
  for (int q=0;q<4;q++) accd[q] = (f32x4){0,0,0,0};
  #pragma unroll
  for (int s=0; s<8; s++){
    int nq = s>>1, kc = s&1;
    #pragma unroll
    for (int kk=0;kk<2;kk++){
      int ch = (kk<<2) + lq;
      bf16x8 afr = frag(Adel + kc*1024, lr, ch);
      bf16x8 bfr = frag(Bbig + s*8192, wid*16 + lr, ch);
      accd[nq] = __builtin_amdgcn_mfma_f32_16x16x32_bf16(afr, bfr, accd[nq], 0,0,0);
    }
  }
  #pragma unroll
  for (int nq=0;nq<4;nq++){
    int col = nq*128 + wid*16 + lr;
    float tb = tdb[col];
    #pragma unroll
    for (int reg=0;reg<4;reg++){
      int row = (lq<<2) + reg;
      float v = accd[nq][reg] + tb;
      inp[(size_t)(r0+row)*704 + col] = tobf(hreg[nq*4+reg] * __expf(-fmaxf(v,0.f)));
    }
  }
}

// ---------- per-step kernel 1: xc only (hdec comes from inp) ----------
// 256 blocks x 512 threads, 16 rows/block, 2 barriers total.
__global__ __launch_bounds__(512) void k_xc2(int t,
    const float* __restrict__ values, const float* __restrict__ masks,
    const short* __restrict__ Wxp,  const float* __restrict__ bxp,
    const float* __restrict__ st,
    short* __restrict__ inp, float* __restrict__ out_imp,
    float* __restrict__ num, float* __restrict__ den){
  __shared__ __align__(16) short A2[10*1024];     // [hdec 512 | x 96 | pad 32]
  __shared__ short sm[16*96];
  __shared__ __align__(16) short Bbig[61440];     // 10 x [96][64]
  __shared__ float wred[8], wred2[8];
  const int tid = threadIdx.x, lane = tid&63, wid = tid>>6;
  const int r0 = blockIdx.x*16;
  const int lr = lane&15, lq = lane>>4;

  float4 xv4, mv4;
  const bool act = tid < 384;
  int ar=0, af0=0;
  if (act){
    ar = tid/24; af0 = (tid - ar*24)*4;
    size_t gb = ((size_t)(r0+ar)*Tn + t)*Fn + af0;
    xv4 = *(const float4*)(values + gb);
    mv4 = *(const float4*)(masks  + gb);
  }
  float streg[4] = {0.f,0.f,0.f,0.f};
  if (wid < 6){
    int f = wid*16 + lr;
    #pragma unroll
    for (int reg=0;reg<4;reg++)
      streg[reg] = st[(size_t)(r0 + (lq<<2) + reg)*Fn + f];
  }

  // stage hdec chunks 0..7 from inp (written by gates(t-1) / dec0)
  for (int c2 = wid; c2 < 16; c2 += 8){
    int chunk = c2 >> 1, rg = c2 & 1;
    int r = rg*8 + (lane>>3);
    int ch = (lane&7) ^ (r&7);
    const short* gp = inp + (size_t)(r0 + r)*704 + chunk*64 + (ch<<3);
    __builtin_amdgcn_global_load_lds(GC(gp), LC(A2 + chunk*1024 + rg*512), 16, 0, 0);
  }
  // stage all Wxp tiles
  #pragma unroll
  for (int kx=0; kx<10; kx++)
    stage_tile(Wxp, 640, kx*64, Bbig + kx*6144, 96, wid, lane, 8);

  // A-build: x -> A2 chunks 8,9; m -> sm + inp[608..]
  if (act){
    #pragma unroll
    for (int j=0;j<4;j++){
      int f = af0 + j;
      float xv = ((const float*)&xv4)[j];
      float mv = ((const float*)&mv4)[j];
      sm[ar*96 + f] = tobf(mv);
      inp[(size_t)(r0+ar)*704 + 608 + f] = tobf(mv);
      A2[haddr(ar, 512+f)] = tobf(xv);
    }
  }
  { int r = tid>>5, cz = tid&31; A2[haddr(r, 608+cz)] = 0; }
  __syncthreads();   // the only staging barrier

  f32x4 accx = (f32x4){0,0,0,0};
  if (wid < 6){
    #pragma unroll
    for (int kx=0; kx<10; kx++)
      #pragma unroll
      for (int kk=0;kk<2;kk++){
        int ch = (kk<<2) + lq;
        bf16x8 afr = frag(A2 + kx*1024, lr, ch);
        bf16x8 bfr = frag(Bbig + kx*6144, wid*16 + lr, ch);
        accx = __builtin_amdgcn_mfma_f32_16x16x32_bf16(afr, bfr, accx, 0,0,0);
      }
  }
  float lsum = 0.f, msum = 0.f;
  if (wid < 6){
    int f = wid*16 + lr;
    float bx = bxp[f];
    #pragma unroll
    for (int reg=0;reg<4;reg++){
      int row = (lq<<2) + reg;
      float xcv = accx[reg] + bx + streg[reg];
      float xv = bf2f(A2[haddr(row, 512+f)]);
      float mv = bf2f(sm[row*96 + f]);
      lsum += fabsf(xv - xcv)*mv;
      msum += mv;
      float cc = mv*xv + (1.f-mv)*xcv;
      inp[(size_t)(r0+row)*704 + 512 + f] = tobf(cc);
      out_imp[((size_t)(r0+row)*Tn + t)*Fn + f] = cc;
    }
  }
  #pragma unroll
  for (int o=32;o>0;o>>=1){ lsum += __shfl_down(lsum, o); msum += __shfl_down(msum, o); }
  if (lane==0){ wred[wid] = lsum; wred2[wid] = msum; }
  __syncthreads();
  if (tid==0){
    float s2 = 0.f, s3 = 0.f;
    #pragma unroll
    for (int w2=0;w2<8;w2++){ s2 += wred[w2]; s3 += wred2[w2]; }
    atomicAdd(&num[t], s2);
    atomicAdd(&den[t], s3);
  }
}

// ---------- per-step kernel 2: gates GEMM + LSTM + gamma(t+1) tail ----------
// reads inpR (step t activations), writes hdec(t+1) into inpW.
__global__ __launch_bounds__(512, 4) void k_gates(int t,
    const short* __restrict__ inpR, short* __restrict__ inpW,
    const short* __restrict__ Wgp, const float* __restrict__ bgp,
    const float* __restrict__ deltas, const short* __restrict__ tdWp,
    const float* __restrict__ tdb,
    float* __restrict__ h_g, float* __restrict__ c_g){
  __shared__ __align__(16) short SMEM[32768];   // 64 KB: dbuf A/B, then gamma pool
  const int tid = threadIdx.x, lane = tid&63, wid = tid>>6;
  const int mb = blockIdx.x & 31, pb = blockIdx.x >> 5;
  const int r0 = mb*128;
  const short* gA = inpR + (size_t)r0*704;
  const short* gB = Wgp + (size_t)pb*128*704;
  const int wM = wid>>1, wN = wid&1, lr = lane&15, lq = lane>>4;
  const bool hg = (t+1 < Tn);
  f32x4 acc[2][4];
  #pragma unroll
  for (int m=0;m<2;m++)
    #pragma unroll
    for (int n=0;n<4;n++) acc[m][n] = (f32x4){0,0,0,0};

  stage_tile(gA, 704, 0, SMEM, 128, wid, lane, 8);
  stage_tile(gB, 704, 0, SMEM + 16384, 128, wid, lane, 8);
  __syncthreads();

  for (int kc=0; kc<11; kc++){
    if (kc < 10){
      stage_tile(gA, 704, (kc+1)*64, SMEM + ((kc+1)&1)*8192, 128, wid, lane, 8);
      stage_tile(gB, 704, (kc+1)*64, SMEM + 16384 + ((kc+1)&1)*8192, 128, wid, lane, 8);
    }
    #pragma unroll
    for (int kk=0;kk<2;kk++){
      int ch = (kk<<2) + lq;
      bf16x8 af[2];
      #pragma unroll
      for (int m=0;m<2;m++) af[m] = frag(SMEM + (kc&1)*8192, wM*32 + m*16 + lr, ch);
      #pragma unroll
      for (int n=0;n<4;n++){
        bf16x8 bf = frag(SMEM + 16384 + (kc&1)*8192, wN*64 + n*16 + lr, ch);
        #pragma unroll
        for (int m=0;m<2;m++)
          acc[m][n] = __builtin_amdgcn_mfma_f32_16x16x32_bf16(af[m], bf, acc[m][n],0,0,0);
      }
    }
    __syncthreads();
  }

  // tail staging: deltas(t+1) regs + tdW panel slice (issued before epilogue VALU)
  float dreg[24];
  const int drow = tid>>2, dc0 = (tid&3)*24;
  if (hg){
    size_t gb = ((size_t)(r0+drow)*Tn + (t+1))*Fn + dc0;
    #pragma unroll
    for (int q=0;q<6;q++){
      float4 v4 = *(const float4*)(deltas + gb + q*4);
      dreg[q*4+0]=v4.x; dreg[q*4+1]=v4.y; dreg[q*4+2]=v4.z; dreg[q*4+3]=v4.w;
    }
    stage_tile(tdWp + (size_t)(pb*32)*128, 128, 0,  SMEM + 16384, 32, wid, lane, 8);
    stage_tile(tdWp + (size_t)(pb*32)*128, 128, 64, SMEM + 18432, 32, wid, lane, 8);
  }

  // fused LSTM epilogue (ncol = jj_local*4 + g; 4-lane shfl transpose)
  const int g = lane&3;
  const float s_  = (g==2) ? 2.0f : -1.0f;
  const float ca_ = (g==2) ? -2.0f : 1.0f;
  const float cb_ = (g==2) ? 1.0f : 0.0f;
  float hnew[2][4];
  #pragma unroll
  for (int m=0;m<2;m++){
    int row = r0 + wM*32 + m*16 + (lq<<2) + g;
    #pragma unroll
    for (int n=0;n<4;n++){
      int colbase = wN*64 + n*16 + lr;
      float b = bgp[pb*128 + colbase];
      float q0 = 1.f/(1.f+__expf(s_*(acc[m][n][0]+b))); float a0 = q0*ca_+cb_;
      float q1 = 1.f/(1.f+__expf(s_*(acc[m][n][1]+b))); float a1 = q1*ca_+cb_;
      float q2 = 1.f/(1.f+__expf(s_*(acc[m][n][2]+b))); float a2 = q2*ca_+cb_;
      float q3 = 1.f/(1.f+__expf(s_*(acc[m][n][3]+b))); float a3 = q3*ca_+cb_;
      int i1=g^1, i2=g^2, i3=g^3;
      float p1 = (i1==0)?a0:(i1==1)?a1:(i1==2)?a2:a3;
      float p2 = (i2==0)?a0:(i2==1)?a1:(i2==2)?a2:a3;
      float p3 = (i3==0)?a0:(i3==1)?a1:(i3==2)?a2:a3;
      float ow = (g==0)?a0:(g==1)?a1:(g==2)?a2:a3;
      float t1 = __shfl_xor(p1, 1, 64);
      float t2 = __shfl_xor(p2, 2, 64);
      float t3 = __shfl_xor(p3, 3, 64);
      float si = (g==0)?ow:(g==1)?t1:(g==2)?t2:t3;
      float sf = (g==1)?ow:(g==0)?t1:(g==3)?t2:t3;
      float tg = (g==2)?ow:(g==3)?t1:(g==0)?t2:t3;
      float so = (g==3)?ow:(g==2)?t1:(g==1)?t2:t3;
      int jh = pb*32 + (colbase>>2);
      size_t idx = (size_t)row*Hn + jh;
      float co = c_g[idx];
      float cn = sf*co + si*tg;
      float targ = fminf(fmaxf(2.0f*cn,-60.f),60.f);
      float e = __expf(targ); float th = (e-1.f)/(e+1.f);
      c_g[idx] = cn;
      float hv = so*th;
      h_g[idx] = hv;
      hnew[m][n] = hv;
    }
  }

  if (hg){
    // deltas -> dA (SMEM, 2 chunks of [128][64]) + zero pad 96..127
    #pragma unroll
    for (int j=0;j<24;j++){
      int cdx = dc0 + j;
      SMEM[haddr128(drow, cdx)] = tobf(dreg[j]);
    }
    #pragma unroll
    for (int j=0;j<8;j++){
      int cdx = 96 + (tid&3)*8 + j;
      SMEM[haddr128(drow, cdx)] = 0;
    }
    __syncthreads();   // dA + tdW slice ready (drains vmcnt)

    // gamma pre-activation GEMM: M=128 (wave wid: rows wid*16..+15), N=32, K=128
    f32x4 gv[2];
    gv[0]=(f32x4){0,0,0,0}; gv[1]=(f32x4){0,0,0,0};
    #pragma unroll
    for (int kc=0;kc<2;kc++)
      #pragma unroll
      for (int kk=0;kk<2;kk++){
        int ch = (kk<<2) + lq;
        bf16x8 afr = frag(SMEM + kc*8192, wid*16 + lr, ch);
        #pragma unroll
        for (int n=0;n<2;n++)
          gv[n] = __builtin_amdgcn_mfma_f32_16x16x32_bf16(afr,
                    frag(SMEM + 16384 + kc*2048, n*16 + lr, ch), gv[n], 0,0,0);
      }
    float* vlds = (float*)(SMEM + 20480);   // [128][33] f32
    #pragma unroll
    for (int n=0;n<2;n++)
      #pragma unroll
      for (int reg=0;reg<4;reg++)
        vlds[(wid*16 + (lq<<2) + reg)*33 + n*16 + lr] = gv[n][reg];
    __syncthreads();

    // hdec(t+1) = hnew * gamma -> inpW
    #pragma unroll
    for (int m=0;m<2;m++){
      int rowl = wM*32 + m*16 + (lq<<2) + g;
      #pragma unroll
      for (int n=0;n<4;n++){
        int jl = (wN*64 + n*16 + lr)>>2;
        float v = vlds[rowl*33 + jl] + tdb[pb*32 + jl];
        float gam = __expf(-fmaxf(v, 0.f));
        inpW[(size_t)(r0+rowl)*704 + pb*32 + jl] = tobf(hnew[m][n] * gam);
      }
    }
  }
}

// ---------- epilogue ----------

__global__ void k_out(const float* __restrict__ h_g, const float* __restrict__ outW,
                      const float* __restrict__ outb, const float* __restrict__ labels,
                      float* __restrict__ out_sig, float* __restrict__ yacc){
  int b = blockIdx.x, lane = threadIdx.x;
  float s = 0.f;
  for (int k = lane; k < Hn; k += 64) s += h_g[(size_t)b*Hn + k] * outW[k];
  #pragma unroll
  for (int o = 32; o > 0; o >>= 1) s += __shfl_down(s, o);
  if (lane == 0){
    float z = s + outb[0];
    out_sig[b] = sigmf_(z);
    float yl = fmaxf(z, 0.f) - z*labels[b] + log1pf(expf(-fabsf(z)));
    atomicAdd(yacc, yl);
  }
}

__global__ void k_loss(const float* __restrict__ realW, const float* __restrict__ histW,
                       const float* __restrict__ stW,   const float* __restrict__ frW,
                       const float* __restrict__ num,   const float* __restrict__ den,
                       const float* __restrict__ yacc,  float* __restrict__ out0){
  int tid = threadIdx.x;
  float r1 = 0.f;
  for (int i = tid; i < Fn*Fn; i += 256) r1 += fabsf(realW[i]);
  for (int i = tid; i < Fn*Hn; i += 256) r1 += fabsf(histW[i]);
  for (int i = tid; i < Fn*Sn; i += 256) r1 += fabsf(stW[i]);
  float rd = 0.f;
  for (int i = tid; i < Fn; i += 256) rd += fabsf(realW[i*Fn + i]);
  float fd = 0.f;
  for (int i = tid; i < Sn; i += 256) fd += fabsf(frW[i*Sn + i]);
  float xl = 0.f;
  for (int t = tid; t < Tn; t += 256) xl += num[t] / (den[t] + 1e-5f);
  float v = 0.01f*r1 + 0.1f*rd + 0.3f*xl + 0.03f*fd;
  __shared__ float red[256];
  red[tid] = v; __syncthreads();
  for (int o = 128; o > 0; o >>= 1){ if (tid < o) red[tid] += red[tid + o]; __syncthreads(); }
  if (tid == 0) out0[0] = red[0] + yacc[0] / (float)Bn;
}

// ---------- launch ----------

extern "C" void kernel_launch(void* const* d_in, const int* in_sizes, int n_in,
                              void* d_out, int out_size, void* d_ws, size_t ws_size,
                              hipStream_t stream){
  const float* values = (const float*)d_in[0];
  const float* masks  = (const float*)d_in[1];
  const float* deltas = (const float*)d_in[2];
  const float* statics= (const float*)d_in[3];
  const float* smask  = (const float*)d_in[4];
  const float* labels = (const float*)d_in[5];
  const float* frW = (const float*)d_in[6];
  const float* frb = (const float*)d_in[7];
  const float* d1W = (const float*)d_in[8];
  const float* d1b = (const float*)d_in[9];
  const float* d2W = (const float*)d_in[10];
  const float* d2b = (const float*)d_in[11];
  const float* d3W = (const float*)d_in[12];
  const float* d3b = (const float*)d_in[13];
  const float* tdW = (const float*)d_in[14];
  const float* tdb = (const float*)d_in[15];
  const float* histW = (const float*)d_in[16];
  const float* histb = (const float*)d_in[17];
  const float* stW = (const float*)d_in[18];
  const float* stb = (const float*)d_in[19];
  const float* realW = (const float*)d_in[20];
  const float* realb = (const float*)d_in[21];
  const float* Wih = (const float*)d_in[22];
  const float* Whh = (const float*)d_in[23];
  const float* bih = (const float*)d_in[24];
  const float* bhh = (const float*)d_in[25];
  const float* outW = (const float*)d_in[26];
  const float* outb = (const float*)d_in[27];

  float* out0    = (float*)d_out;
  float* out_sig = out0 + 1;
  float* out_imp = out0 + 1 + Bn;

  float* wsf  = (float*)d_ws;
  float* s_c  = wsf;  wsf += Bn*Sn;
  float* h    = wsf;  wsf += (size_t)Bn*Hn;
  float* c    = wsf;  wsf += (size_t)Bn*Hn;
  float* st   = wsf;  wsf += Bn*Fn;
  float* den  = wsf;  wsf += Tn;
  float* num  = wsf;  wsf += Tn;
  float* yacc = num + Tn;           // den/num/yacc contiguous, zeroed together
  wsf += 1;
  float* bxp  = wsf;  wsf += 128;
  float* bgp  = wsf;  wsf += 2048;
  size_t off = ((size_t)(wsf - (float*)d_ws) + 3u) & ~(size_t)3u;
  short* wss  = (short*)((float*)d_ws + off);
  short* tdWp = wss;  wss += 512*128;
  short* Wxp  = wss;  wss += 96*640;
  short* Wgp  = wss;  wss += (size_t)16*128*704;
  short* inp0 = wss;  wss += (size_t)Bn*704;
  short* inp1 = wss;  wss += (size_t)Bn*704;
  short* wd1  = wss;  wss += 512*128;
  short* wd2  = wss;  wss += 512*512;
  short* wd3  = wss;  wss += 512*512;
  short* act0 = wss;  wss += (size_t)Bn*128;
  short* actA = wss;  wss += (size_t)Bn*512;
  short* actB = wss;  wss += (size_t)Bn*512;

  hipMemsetAsync(c,   0, (size_t)Bn*Hn*sizeof(float), stream);
  hipMemsetAsync(den, 0, (2*Tn + 1)*sizeof(float), stream);

  // prepacks
  k_pack_td<<<(512*128+255)/256, 256, 0, stream>>>(tdW, tdWp);
  k_pack_x <<<(96*640+255)/256, 256, 0, stream>>>(realW, histW, realb, histb, Wxp, bxp);
  k_pack_g<<<(16*128*704+255)/256, 256, 0, stream>>>(Wih, Whh, bih, bhh, Wgp, bgp);
  k_cvt<<<(512*128+255)/256, 256, 0, stream>>>(d1W, wd1, 512*128);
  k_cvt<<<(512*512+255)/256, 256, 0, stream>>>(d2W, wd2, 512*512);
  k_cvt<<<(512*512+255)/256, 256, 0, stream>>>(d3W, wd3, 512*512);

  // prologue math: static imputation + MFMA MLP chain
  k_static<<<Bn, Sn, 0, stream>>>(statics, smask, frW, frb, s_c);
  k_cvt<<<(Bn*Sn+255)/256, 256, 0, stream>>>(s_c, act0, Bn*Sn);
  k_gemm<128, true,  false><<<128, 512, 0, stream>>>(act0, wd1, d1b, actA, (float*)nullptr);
  k_gemm<512, true,  false><<<128, 512, 0, stream>>>(actA, wd2, d2b, actB, (float*)nullptr);
  k_gemm<512, true,  true ><<<128, 512, 0, stream>>>(actB, wd3, d3b, actA, h);
  k_mlp<Sn, Fn, false><<<Bn, 256, 0, stream>>>(s_c, stW, stb, st);

  // bootstrap hdec(0) into inp0
  k_dec0<<<Bn/16, 512, 0, stream>>>(deltas, tdWp, tdb, h, inp0);

  // scan: 2 dispatches per step; inp double-buffered by step parity
  for (int t = 0; t < Tn; t++){
    short* iR = (t & 1) ? inp1 : inp0;
    short* iW = (t & 1) ? inp0 : inp1;
    k_xc2  <<<Bn/16,       512, 0, stream>>>(t, values, masks, Wxp, bxp, st,
                                             iR, out_imp, num, den);
    k_gates<<<(Bn/128)*16, 512, 0, stream>>>(t, iR, iW, Wgp, bgp,
                                             deltas, tdWp, tdb, h, c);
  }

  k_out<<<Bn, 64, 0, stream>>>(h, outW, outb, labels, out_sig, yacc);
  k_loss<<<1, 256, 0, stream>>>(realW, histW, stW, frW, num, den, yacc, out0);
}